// Round 11
// baseline (148.115 us; speedup 1.0000x reference)
//
#include <hip/hip_runtime.h>
#include <stdint.h>
#include <math.h>

// ---------------- problem constants ----------------
constexpr int D_ = 128;                 // quantum_dim
constexpr int KDIM = 4096;              // S / NQ
constexpr uint32_t NTH = 4096u * 128u;  // total threads = 524288
// flat index n = kk*128 + d + b*2^23 + q*2^19

#define DELTA   0.00385f                // covers nc*max|normal| = 3.814e-3 (+1% slack)
#define RELM    1.0002f                 // in-thread mask margin (t~ rel err + rcp err)
#define WLO_PAD 1e-3f                   // W_lo extra lower-bound pad
#define EPS_CMP 1e-3f                   // K2b quick-reject window

// ---------------- threefry2x32 (JAX-exact, 20 rounds) ----------------
__host__ __device__ static inline void tfround(uint32_t& x0, uint32_t& x1, int r) {
    x0 += x1;
    x1 = (x1 << r) | (x1 >> (32 - r));   // compiler emits v_alignbit_b32
    x1 ^= x0;
}

__host__ __device__ static inline void tf2x32(uint32_t k0, uint32_t k1,
                                              uint32_t x0, uint32_t x1,
                                              uint32_t& o0, uint32_t& o1) {
    uint32_t ks2 = k0 ^ k1 ^ 0x1BD11BDAu;
    x0 += k0; x1 += k1;
    tfround(x0, x1, 13); tfround(x0, x1, 15); tfround(x0, x1, 26); tfround(x0, x1, 6);
    x0 += k1;  x1 += ks2 + 1u;
    tfround(x0, x1, 17); tfround(x0, x1, 29); tfround(x0, x1, 16); tfround(x0, x1, 24);
    x0 += ks2; x1 += k0 + 2u;
    tfround(x0, x1, 13); tfround(x0, x1, 15); tfround(x0, x1, 26); tfround(x0, x1, 6);
    x0 += k0;  x1 += k1 + 3u;
    tfround(x0, x1, 17); tfround(x0, x1, 29); tfround(x0, x1, 16); tfround(x0, x1, 24);
    x0 += k1;  x1 += ks2 + 4u;
    tfround(x0, x1, 13); tfround(x0, x1, 15); tfround(x0, x1, 26); tfround(x0, x1, 6);
    x0 += ks2; x1 += k0 + 5u;
    o0 = x0; o1 = x1;
}

// t = -ln(u): 5-term series for nz<0.01 (avoids v_log cancellation), v_log otherwise.
__device__ __forceinline__ float neglog_hybrid(float u, float nz) {
    float p4 = fmaf(nz, 0.2f, 0.25f);
    float p3 = fmaf(nz, p4, 0.33333334f);
    float p2 = fmaf(nz, p3, 0.5f);
    float poly = fmaf(nz, p2, 1.0f);
    float ts = nz * poly;
    float tl = -__logf(u);
    return (nz < 0.01f) ? ts : tl;
}

// erfinv, Giles polynomial; hw log everywhere (tail uses Sterbenz-exact (1-x)(1+x)).
__device__ __forceinline__ float erfinv_fast(float x) {
    float w = -__logf(fmaf(-x, x, 1.0f));
    float p;
    if (w < 5.0f) {
        w -= 2.5f;
        p = 2.81022636e-08f;
        p = fmaf(p, w, 3.43273939e-07f);
        p = fmaf(p, w, -3.5233877e-06f);
        p = fmaf(p, w, -4.39150654e-06f);
        p = fmaf(p, w, 0.00021858087f);
        p = fmaf(p, w, -0.00125372503f);
        p = fmaf(p, w, -0.00417768164f);
        p = fmaf(p, w, 0.246640727f);
        p = fmaf(p, w, 1.50140941f);
    } else {
        float wt = -__logf((1.0f - x) * (1.0f + x));
        float v = sqrtf(wt) - 3.0f;
        p = -0.000200214257f;
        p = fmaf(p, v, 0.000100950558f);
        p = fmaf(p, v, 0.00134934322f);
        p = fmaf(p, v, -0.00367342844f);
        p = fmaf(p, v, 0.00573950773f);
        p = fmaf(p, v, -0.0076224613f);
        p = fmaf(p, v, 0.00943887047f);
        p = fmaf(p, v, 1.00167406f);
        p = fmaf(p, v, 2.83297682f);
    }
    return p * x;
}

// order-preserving float->uint map (and inverse)
__device__ __forceinline__ uint32_t ordmap(float x) {
    uint32_t u = __float_as_uint(x);
    return (u & 0x80000000u) ? ~u : (u | 0x80000000u);
}
__device__ __forceinline__ float ordunmap(uint32_t m) {
    uint32_t u = (m & 0x80000000u) ? (m & 0x7FFFFFFFu) : ~m;
    return __uint_as_float(u);
}

// ---------------- kernel 1: prep (C = coh*(0.8*softmax(ent)+0.2*I), phase, zero) ----
__global__ __launch_bounds__(512) void qsl_prep(const float* __restrict__ ang,
                                                const float* __restrict__ ent,
                                                float* __restrict__ ws_f,
                                                unsigned long long* __restrict__ keys,
                                                uint32_t* __restrict__ Mlo,
                                                float coh) {
    __shared__ float sm[16][16];
    int t = threadIdx.x;
    keys[t] = 0ULL;
    if (t < 512) Mlo[t] = 0u;
    if (t < 16) {
        float row[16];
        float m = -INFINITY;
        for (int j = 0; j < 16; j++) { row[j] = ent[t * 16 + j]; m = fmaxf(m, row[j]); }
        float s = 0.f;
        for (int j = 0; j < 16; j++) { row[j] = expf(row[j] - m); s += row[j]; }
        float inv = 1.0f / s;
        for (int j = 0; j < 16; j++) sm[t][j] = row[j] * inv;
    }
    if (t == 0) {
        float a = 0.f;
        for (int i = 0; i < 48; i++) a += ang[i];
        ws_f[256] = cosf(a);
        ws_f[257] = sinf(a);
    }
    __syncthreads();
    if (t < 256) {
        int q = t >> 4, p = t & 15;
        float c = (0.8f * coh) * sm[q][p];
        if (q == p) c += 0.2f * coh;
        ws_f[t] = c;
    }
}

// ---------------- kernel 2a: bounds pass (no LDS, no exact evals) ----------------
__global__ __launch_bounds__(256) void qsl_bound(const float* __restrict__ qre,
                                                 const float* __restrict__ qim,
                                                 const float* __restrict__ Cg,
                                                 uint32_t* __restrict__ Mlo,
                                                 unsigned long long* __restrict__ maskArr,
                                                 float4* __restrict__ whiArr,
                                                 uint32_t kC0, uint32_t kC1) {
    const int d = threadIdx.x;               // 0..127
    const int y = threadIdx.y;               // 0..1
    const int kk = blockIdx.x * 2 + y;       // 0..4095
    const uint32_t g = (uint32_t)kk * 128u + (uint32_t)d;

    // hoisted, stale-safe Mlo snapshot (atomic-avoidance filter only)
    uint32_t mcur0 = Mlo[0 * 128 + d];
    uint32_t mcur1 = Mlo[1 * 128 + d];
    uint32_t mcur2 = Mlo[2 * 128 + d];
    uint32_t mcur3 = Mlo[3 * 128 + d];

    const float pr = Cg[256], pi = Cg[257];

    // ---- phase A: mix once, keep only per-q exp-domain bound factors
    float eLo[16], eHi[16];
    {
        float vr[16], vi[16];
#pragma unroll
        for (int p = 0; p < 16; p++) {
            int off = (p * KDIM + kk) * D_ + d;
            float ar = qre[off], ai = qim[off];
            vr[p] = fmaf(pr, ar, -(pi * ai));
            vi[p] = fmaf(pi, ar, pr * ai);
        }
#pragma unroll
        for (int q = 0; q < 16; q++) {
            float br = 0.f, bi = 0.f;
#pragma unroll
            for (int p = 0; p < 16; p++) {
                float c = Cg[q * 16 + p];        // uniform -> s_load
                br = fmaf(c, vr[p], br);
                bi = fmaf(c, vi[p], bi);
            }
            float abr = fabsf(br), abi = fabsf(bi);
            float hr = abr + DELTA, hq = abi + DELTA;
            float Phi_hi = fmaf(hr, hr, fmaf(hq, hq, 1e-20f));
            float lr = fmaxf(abr - DELTA, 0.f), lq = fmaxf(abi - DELTA, 0.f);
            float Phi_lo = fmaf(lr, lr, fmaf(lq, lq, 1e-20f));
            eLo[q] = __builtin_amdgcn_rcpf(Phi_lo);
            eHi[q] = __builtin_amdgcn_rcpf(Phi_hi);
        }
    }

    unsigned long long mask64 = 0ull;
    float wlo_a[4], whi_a[4];

#pragma unroll 1
    for (int b = 0; b < 4; b++) {
        const uint32_t nb = g + ((uint32_t)b << 23);
        float ph[16];
        float mlo_t = INFINITY, mhi_t = INFINITY;
#pragma unroll
        for (int q = 0; q < 16; q++) {
            uint32_t w0, w1;
            tf2x32(kC0, kC1, 0u, nb + ((uint32_t)q << 19), w0, w1);
            uint32_t r = w0 ^ w1;
            float f = __uint_as_float((r >> 9) | 0x3f800000u) - 1.0f;
            float nz = 1.0f - f;
            float t = neglog_hybrid(f, nz);      // t~ = -ln f; ~= -ln u to 1e-7
            float plo = t * eLo[q];
            float phi_ = t * eHi[q];
            ph[q] = phi_;
            mlo_t = fminf(mlo_t, plo);
            mhi_t = fminf(mhi_t, phi_);
        }
        uint32_t mloc = 0u;
        float thr = mlo_t * RELM;
#pragma unroll
        for (int q = 0; q < 16; q++)
            if (ph[q] <= thr) mloc |= (1u << q);  // winner provably included
        mask64 |= ((unsigned long long)mloc) << (b * 16);

        wlo_a[b] = -__logf(mlo_t) - WLO_PAD;      // sound lower bound of thread's max v
        whi_a[b] = -__logf(mhi_t);                // sound upper bound
    }

    // ---- epilogue: coalesced stores + rare atomic publishes
    maskArr[g] = mask64;
    whiArr[g] = make_float4(whi_a[0], whi_a[1], whi_a[2], whi_a[3]);

    uint32_t mu0 = ordmap(wlo_a[0]);
    uint32_t mu1 = ordmap(wlo_a[1]);
    uint32_t mu2 = ordmap(wlo_a[2]);
    uint32_t mu3 = ordmap(wlo_a[3]);
    if (mu0 > mcur0) atomicMax(&Mlo[0 * 128 + d], mu0);
    if (mu1 > mcur1) atomicMax(&Mlo[1 * 128 + d], mu1);
    if (mu2 > mcur2) atomicMax(&Mlo[2 * 128 + d], mu2);
    if (mu3 > mcur3) atomicMax(&Mlo[3 * 128 + d], mu3);
}

// ---------------- kernel 2b: resolve (exact eval only for global candidates) ----
__global__ __launch_bounds__(256) void qsl_resolve(const float* __restrict__ qre,
                                                   const float* __restrict__ qim,
                                                   const float* __restrict__ Cg,
                                                   const uint32_t* __restrict__ Mlo,
                                                   const unsigned long long* __restrict__ maskArr,
                                                   const float4* __restrict__ whiArr,
                                                   unsigned long long* __restrict__ keys,
                                                   uint32_t kA0, uint32_t kA1,
                                                   uint32_t kB0, uint32_t kB1,
                                                   uint32_t kC0, uint32_t kC1,
                                                   float nc) {
    const int d = threadIdx.x;
    const int y = threadIdx.y;
    const int kk = blockIdx.x * 2 + y;
    const uint32_t g = (uint32_t)kk * 128u + (uint32_t)d;

    // all prune inputs issued together
    unsigned long long mask64 = maskArr[g];
    float4 whi4 = whiArr[g];
    uint32_t m0 = Mlo[0 * 128 + d];
    uint32_t m1 = Mlo[1 * 128 + d];
    uint32_t m2 = Mlo[2 * 128 + d];
    uint32_t m3 = Mlo[3 * 128 + d];

    unsigned long long live = 0ull;
    if (!(whi4.x < ordunmap(m0) - EPS_CMP)) live |= 0xFFFFull;
    if (!(whi4.y < ordunmap(m1) - EPS_CMP)) live |= 0xFFFFull << 16;
    if (!(whi4.z < ordunmap(m2) - EPS_CMP)) live |= 0xFFFFull << 32;
    if (!(whi4.w < ordunmap(m3) - EPS_CMP)) live |= 0xFFFFull << 48;
    mask64 &= live;
    if (mask64 == 0ull) return;                    // >=99.9% of threads exit here

    // survivor: rebuild phase-folded amplitudes (bit-identical chain to qsl_bound)
    const float pr = Cg[256], pi = Cg[257];
    float vr[16], vi[16];
#pragma unroll
    for (int p = 0; p < 16; p++) {
        int off = (p * KDIM + kk) * D_ + d;
        float ar = qre[off], ai = qim[off];
        vr[p] = fmaf(pr, ar, -(pi * ai));
        vi[p] = fmaf(pi, ar, pr * ai);
    }

    const float ULO = 1e-7f;
    const float UDF = 1.0f - 1e-7f;
    const float NLO = -0.99999994f;
    const float NDF = 1.0f - NLO;

    while (mask64) {
        int bit = __ffsll(mask64) - 1;
        mask64 &= mask64 - 1ull;
        uint32_t q = (uint32_t)bit & 15u;
        int b = bit >> 4;
        uint32_t n = g + ((uint32_t)bit << 19);

        // mix: same fmaf order as qsl_bound (bit-identical br/bi)
        float br = 0.f, bi = 0.f;
        const float4* C4 = reinterpret_cast<const float4*>(Cg + (q << 4));
#pragma unroll
        for (int j = 0; j < 4; j++) {
            float4 c = C4[j];
            br = fmaf(c.x, vr[j*4+0], br); bi = fmaf(c.x, vi[j*4+0], bi);
            br = fmaf(c.y, vr[j*4+1], br); bi = fmaf(c.y, vi[j*4+1], bi);
            br = fmaf(c.z, vr[j*4+2], br); bi = fmaf(c.z, vi[j*4+2], bi);
            br = fmaf(c.w, vr[j*4+3], br); bi = fmaf(c.w, vi[j*4+3], bi);
        }

        uint32_t w0, w1;
        tf2x32(kC0, kC1, 0u, n, w0, w1);
        uint32_t rC = w0 ^ w1;
        tf2x32(kA0, kA1, 0u, n, w0, w1);
        uint32_t rA = w0 ^ w1;
        tf2x32(kB0, kB1, 0u, n, w0, w1);
        uint32_t rB = w0 ^ w1;

        float fu = __uint_as_float((rC >> 9) | 0x3f800000u) - 1.0f;
        float u  = __fadd_rn(__fmul_rn(fu, UDF), ULO);    // exact JAX u
        float f0 = __uint_as_float((rA >> 9) | 0x3f800000u) - 1.0f;
        float x0 = __fadd_rn(__fmul_rn(f0, NDF), NLO);
        float f1 = __uint_as_float((rB >> 9) | 0x3f800000u) - 1.0f;
        float x1 = __fadd_rn(__fmul_rn(f1, NDF), NLO);
        float nr = 1.41421356f * erfinv_fast(x0);
        float ni = 1.41421356f * erfinv_fast(x1);
        float ar = fmaf(nc, nr, br);
        float ai = fmaf(nc, ni, bi);
        float logit = __logf(fmaf(ar, ar, fmaf(ai, ai, 1e-20f)));
        float nz = 1.0f - u;
        float t = neglog_hybrid(u, nz);
        float gv = __logf(t);
        float v = logit - gv;

        uint32_t s = (q << 12) + (uint32_t)kk;
        uint32_t mu = ordmap(v);
        unsigned long long kp =
            ((unsigned long long)mu << 32) |
            (unsigned long long)(0xFFFFFFFFu - s);         // tie -> smaller s wins
        atomicMax(&keys[b * 128 + d], kp);
    }
}

// ---------------- kernel 3: gather hits + bias mean ----------------
__global__ __launch_bounds__(128) void qsl_out(const unsigned long long* __restrict__ keys,
                                               const float* __restrict__ mW,
                                               const float* __restrict__ mb,
                                               float* __restrict__ out) {
    int b = blockIdx.x, e = threadIdx.x;
    __shared__ uint32_t idx_s[128];
    unsigned long long kp = keys[b * 128 + e];
    idx_s[e] = 0xFFFFFFFFu - (uint32_t)(kp & 0xFFFFFFFFull);
    __syncthreads();

    float acc = 0.f;
#pragma unroll
    for (int n = 0; n < 16; n++) acc += mb[n * 128 + e];
    for (int dd = 0; dd < 128; dd++) {
        uint32_t m = idx_s[dd];
        if (m < 16u) acc += mW[(m * 128 + e) * 128 + dd];
    }
    out[b * 128 + e] = acc * 0.0625f;
}

// ---------------- launcher ----------------
extern "C" void kernel_launch(void* const* d_in, const int* in_sizes, int n_in,
                              void* d_out, int out_size, void* d_ws, size_t ws_size,
                              hipStream_t stream) {
    (void)in_sizes; (void)n_in; (void)out_size; (void)ws_size;
    const float* qre = (const float*)d_in[1];
    const float* qim = (const float*)d_in[2];
    const float* ang = (const float*)d_in[3];
    const float* ent = (const float*)d_in[4];
    const float* mW  = (const float*)d_in[5];
    const float* mb  = (const float*)d_in[6];
    float* out = (float*)d_out;

    char* ws = (char*)d_ws;
    float* ws_f = (float*)ws;                                      // C[256] + phase[2]
    unsigned long long* keys = (unsigned long long*)(ws + 4096);   // 512 slots
    uint32_t* Mlo = (uint32_t*)(ws + 8192);                        // 512 slots
    unsigned long long* maskArr = (unsigned long long*)(ws + 12288);            // 4 MB
    float4* whiArr = (float4*)(ws + 12288 + (size_t)NTH * 8);                   // 8 MB

    uint32_t kn[6];
    tf2x32(0u, 1u, 0u, 0u, kn[0], kn[1]);
    tf2x32(0u, 1u, 0u, 1u, kn[2], kn[3]);
    tf2x32(0u, 1u, 0u, 2u, kn[4], kn[5]);

    float coh = expf(-0.01f);
    float nc  = (0.70710678f * (1.0f - coh)) * 0.1f;

    hipLaunchKernelGGL(qsl_prep, dim3(1), dim3(512), 0, stream, ang, ent, ws_f, keys, Mlo, coh);
    hipLaunchKernelGGL(qsl_bound, dim3(2048), dim3(128, 2), 0, stream,
                       qre, qim, ws_f, Mlo, maskArr, whiArr, kn[4], kn[5]);
    hipLaunchKernelGGL(qsl_resolve, dim3(2048), dim3(128, 2), 0, stream,
                       qre, qim, ws_f, Mlo, maskArr, whiArr, keys,
                       kn[0], kn[1], kn[2], kn[3], kn[4], kn[5], nc);
    hipLaunchKernelGGL(qsl_out, dim3(4), dim3(128), 0, stream, keys, mW, mb, out);
}

// Round 12
// 114.775 us; speedup vs baseline: 1.2905x; 1.2905x over previous
//
#include <hip/hip_runtime.h>
#include <stdint.h>
#include <math.h>

// ---------------- problem constants ----------------
constexpr int D_ = 128;                 // quantum_dim
constexpr int KDIM = 4096;              // S / NQ
constexpr uint32_t NTH = 4096u * 128u;  // total threads = 524288
// flat index n = kk*128 + d + b*2^23 + q*2^19

#define DELTA   0.00385f                // covers nc*max|normal| = 3.814e-3 (+1% slack)
#define RELM    1.0002f                 // in-thread mask margin (t~ rel err + rcp err)
#define WLO_PAD 1e-3f                   // W_lo extra lower-bound pad
#define EPS_CMP 1e-3f                   // K2b quick-reject window

// ---------------- threefry2x32 (JAX-exact, 20 rounds) ----------------
__host__ __device__ static inline void tfround(uint32_t& x0, uint32_t& x1, int r) {
    x0 += x1;
    x1 = (x1 << r) | (x1 >> (32 - r));   // compiler emits v_alignbit_b32
    x1 ^= x0;
}

__host__ __device__ static inline void tf2x32(uint32_t k0, uint32_t k1,
                                              uint32_t x0, uint32_t x1,
                                              uint32_t& o0, uint32_t& o1) {
    uint32_t ks2 = k0 ^ k1 ^ 0x1BD11BDAu;
    x0 += k0; x1 += k1;
    tfround(x0, x1, 13); tfround(x0, x1, 15); tfround(x0, x1, 26); tfround(x0, x1, 6);
    x0 += k1;  x1 += ks2 + 1u;
    tfround(x0, x1, 17); tfround(x0, x1, 29); tfround(x0, x1, 16); tfround(x0, x1, 24);
    x0 += ks2; x1 += k0 + 2u;
    tfround(x0, x1, 13); tfround(x0, x1, 15); tfround(x0, x1, 26); tfround(x0, x1, 6);
    x0 += k0;  x1 += k1 + 3u;
    tfround(x0, x1, 17); tfround(x0, x1, 29); tfround(x0, x1, 16); tfround(x0, x1, 24);
    x0 += k1;  x1 += ks2 + 4u;
    tfround(x0, x1, 13); tfround(x0, x1, 15); tfround(x0, x1, 26); tfround(x0, x1, 6);
    x0 += ks2; x1 += k0 + 5u;
    o0 = x0; o1 = x1;
}

// t = -ln(u): 5-term series for nz<0.01 (avoids v_log cancellation), v_log otherwise.
__device__ __forceinline__ float neglog_hybrid(float u, float nz) {
    float p4 = fmaf(nz, 0.2f, 0.25f);
    float p3 = fmaf(nz, p4, 0.33333334f);
    float p2 = fmaf(nz, p3, 0.5f);
    float poly = fmaf(nz, p2, 1.0f);
    float ts = nz * poly;
    float tl = -__logf(u);
    return (nz < 0.01f) ? ts : tl;
}

// erfinv, Giles polynomial; hw log everywhere (tail uses Sterbenz-exact (1-x)(1+x)).
__device__ __forceinline__ float erfinv_fast(float x) {
    float w = -__logf(fmaf(-x, x, 1.0f));
    float p;
    if (w < 5.0f) {
        w -= 2.5f;
        p = 2.81022636e-08f;
        p = fmaf(p, w, 3.43273939e-07f);
        p = fmaf(p, w, -3.5233877e-06f);
        p = fmaf(p, w, -4.39150654e-06f);
        p = fmaf(p, w, 0.00021858087f);
        p = fmaf(p, w, -0.00125372503f);
        p = fmaf(p, w, -0.00417768164f);
        p = fmaf(p, w, 0.246640727f);
        p = fmaf(p, w, 1.50140941f);
    } else {
        float wt = -__logf((1.0f - x) * (1.0f + x));
        float v = sqrtf(wt) - 3.0f;
        p = -0.000200214257f;
        p = fmaf(p, v, 0.000100950558f);
        p = fmaf(p, v, 0.00134934322f);
        p = fmaf(p, v, -0.00367342844f);
        p = fmaf(p, v, 0.00573950773f);
        p = fmaf(p, v, -0.0076224613f);
        p = fmaf(p, v, 0.00943887047f);
        p = fmaf(p, v, 1.00167406f);
        p = fmaf(p, v, 2.83297682f);
    }
    return p * x;
}

// order-preserving float->uint map (and inverse)
__device__ __forceinline__ uint32_t ordmap(float x) {
    uint32_t u = __float_as_uint(x);
    return (u & 0x80000000u) ? ~u : (u | 0x80000000u);
}
__device__ __forceinline__ float ordunmap(uint32_t m) {
    uint32_t u = (m & 0x80000000u) ? (m & 0x7FFFFFFFu) : ~m;
    return __uint_as_float(u);
}

// ---------------- kernel 1: prep (C = coh*(0.8*softmax(ent)+0.2*I), phase, zero) ----
__global__ __launch_bounds__(512) void qsl_prep(const float* __restrict__ ang,
                                                const float* __restrict__ ent,
                                                float* __restrict__ ws_f,
                                                unsigned long long* __restrict__ keys,
                                                uint32_t* __restrict__ Mlo,
                                                float coh) {
    __shared__ float sm[16][16];
    int t = threadIdx.x;
    keys[t] = 0ULL;
    if (t < 512) Mlo[t] = 0u;
    if (t < 16) {
        float row[16];
        float m = -INFINITY;
        for (int j = 0; j < 16; j++) { row[j] = ent[t * 16 + j]; m = fmaxf(m, row[j]); }
        float s = 0.f;
        for (int j = 0; j < 16; j++) { row[j] = expf(row[j] - m); s += row[j]; }
        float inv = 1.0f / s;
        for (int j = 0; j < 16; j++) sm[t][j] = row[j] * inv;
    }
    if (t == 0) {
        float a = 0.f;
        for (int i = 0; i < 48; i++) a += ang[i];
        ws_f[256] = cosf(a);
        ws_f[257] = sinf(a);
    }
    __syncthreads();
    if (t < 256) {
        int q = t >> 4, p = t & 15;
        float c = (0.8f * coh) * sm[q][p];
        if (q == p) c += 0.2f * coh;
        ws_f[t] = c;
    }
}

// ---------------- kernel 2a: bounds pass (no LDS, no exact evals) ----------------
__global__ __launch_bounds__(256) void qsl_bound(const float* __restrict__ qre,
                                                 const float* __restrict__ qim,
                                                 const float* __restrict__ Cg,
                                                 uint32_t* __restrict__ Mlo,
                                                 unsigned long long* __restrict__ maskArr,
                                                 float4* __restrict__ whiArr,
                                                 uint32_t kC0, uint32_t kC1) {
    const int d = threadIdx.x;               // 0..127
    const int y = threadIdx.y;               // 0..1
    const int kk = blockIdx.x * 2 + y;       // 0..4095
    const uint32_t g = (uint32_t)kk * 128u + (uint32_t)d;

    const float pr = Cg[256], pi = Cg[257];

    // ---- phase A: mix once, keep only per-q exp-domain bound factors
    float eLo[16], eHi[16];
    {
        float vr[16], vi[16];
#pragma unroll
        for (int p = 0; p < 16; p++) {
            int off = (p * KDIM + kk) * D_ + d;
            float ar = qre[off], ai = qim[off];
            vr[p] = fmaf(pr, ar, -(pi * ai));
            vi[p] = fmaf(pi, ar, pr * ai);
        }
#pragma unroll
        for (int q = 0; q < 16; q++) {
            float br = 0.f, bi = 0.f;
#pragma unroll
            for (int p = 0; p < 16; p++) {
                float c = Cg[q * 16 + p];        // uniform -> s_load
                br = fmaf(c, vr[p], br);
                bi = fmaf(c, vi[p], bi);
            }
            float abr = fabsf(br), abi = fabsf(bi);
            float hr = abr + DELTA, hq = abi + DELTA;
            float Phi_hi = fmaf(hr, hr, fmaf(hq, hq, 1e-20f));
            float lr = fmaxf(abr - DELTA, 0.f), lq = fmaxf(abi - DELTA, 0.f);
            float Phi_lo = fmaf(lr, lr, fmaf(lq, lq, 1e-20f));
            eLo[q] = __builtin_amdgcn_rcpf(Phi_lo);
            eHi[q] = __builtin_amdgcn_rcpf(Phi_hi);
        }
    }

    unsigned long long mask64 = 0ull;
    float whi_a[4];

#pragma unroll 1
    for (int b = 0; b < 4; b++) {
        const uint32_t nb = g + ((uint32_t)b << 23);
        float ph[16];
        float mlo_t = INFINITY, mhi_t = INFINITY;
#pragma unroll
        for (int q = 0; q < 16; q++) {
            uint32_t w0, w1;
            tf2x32(kC0, kC1, 0u, nb + ((uint32_t)q << 19), w0, w1);
            uint32_t r = w0 ^ w1;
            float f = __uint_as_float((r >> 9) | 0x3f800000u) - 1.0f;
            float nz = 1.0f - f;
            float t = neglog_hybrid(f, nz);      // t~ = -ln f; ~= -ln u to 1e-7
            float plo = t * eLo[q];
            float phi_ = t * eHi[q];
            ph[q] = phi_;
            mlo_t = fminf(mlo_t, plo);
            mhi_t = fminf(mhi_t, phi_);
        }
        uint32_t mloc = 0u;
        float thr = mlo_t * RELM;
#pragma unroll
        for (int q = 0; q < 16; q++)
            if (ph[q] <= thr) mloc |= (1u << q);  // winner provably included
        mask64 |= ((unsigned long long)mloc) << (b * 16);

        float wlo = -__logf(mlo_t) - WLO_PAD;     // sound lower bound of thread's max v
        whi_a[b]  = -__logf(mhi_t);               // sound upper bound
        // r10-style FRESH guard load at decision time: filter stays effective,
        // publishes stay rare. Do NOT hoist this to kernel top (r11 regression).
        uint32_t mu = ordmap(wlo);
        uint32_t cur = Mlo[b * 128 + d];          // stale-safe plain load
        if (mu > cur) atomicMax(&Mlo[b * 128 + d], mu);
    }

    // ---- epilogue: coalesced stores
    maskArr[g] = mask64;
    whiArr[g] = make_float4(whi_a[0], whi_a[1], whi_a[2], whi_a[3]);
}

// ---------------- kernel 2b: resolve (exact eval only for global candidates) ----
__global__ __launch_bounds__(256) void qsl_resolve(const float* __restrict__ qre,
                                                   const float* __restrict__ qim,
                                                   const float* __restrict__ Cg,
                                                   const uint32_t* __restrict__ Mlo,
                                                   const unsigned long long* __restrict__ maskArr,
                                                   const float4* __restrict__ whiArr,
                                                   unsigned long long* __restrict__ keys,
                                                   uint32_t kA0, uint32_t kA1,
                                                   uint32_t kB0, uint32_t kB1,
                                                   uint32_t kC0, uint32_t kC1,
                                                   float nc) {
    const int d = threadIdx.x;
    const int y = threadIdx.y;
    const int kk = blockIdx.x * 2 + y;
    const uint32_t g = (uint32_t)kk * 128u + (uint32_t)d;

    // all prune inputs issued together
    unsigned long long mask64 = maskArr[g];
    float4 whi4 = whiArr[g];
    uint32_t m0 = Mlo[0 * 128 + d];
    uint32_t m1 = Mlo[1 * 128 + d];
    uint32_t m2 = Mlo[2 * 128 + d];
    uint32_t m3 = Mlo[3 * 128 + d];

    unsigned long long live = 0ull;
    if (!(whi4.x < ordunmap(m0) - EPS_CMP)) live |= 0xFFFFull;
    if (!(whi4.y < ordunmap(m1) - EPS_CMP)) live |= 0xFFFFull << 16;
    if (!(whi4.z < ordunmap(m2) - EPS_CMP)) live |= 0xFFFFull << 32;
    if (!(whi4.w < ordunmap(m3) - EPS_CMP)) live |= 0xFFFFull << 48;
    mask64 &= live;
    if (mask64 == 0ull) return;                    // >=99.9% of threads exit here

    // survivor: rebuild phase-folded amplitudes (bit-identical chain to qsl_bound)
    const float pr = Cg[256], pi = Cg[257];
    float vr[16], vi[16];
#pragma unroll
    for (int p = 0; p < 16; p++) {
        int off = (p * KDIM + kk) * D_ + d;
        float ar = qre[off], ai = qim[off];
        vr[p] = fmaf(pr, ar, -(pi * ai));
        vi[p] = fmaf(pi, ar, pr * ai);
    }

    const float ULO = 1e-7f;
    const float UDF = 1.0f - 1e-7f;
    const float NLO = -0.99999994f;
    const float NDF = 1.0f - NLO;

    while (mask64) {
        int bit = __ffsll(mask64) - 1;
        mask64 &= mask64 - 1ull;
        uint32_t q = (uint32_t)bit & 15u;
        int b = bit >> 4;
        uint32_t n = g + ((uint32_t)bit << 19);

        // mix: same fmaf order as qsl_bound (bit-identical br/bi)
        float br = 0.f, bi = 0.f;
        const float4* C4 = reinterpret_cast<const float4*>(Cg + (q << 4));
#pragma unroll
        for (int j = 0; j < 4; j++) {
            float4 c = C4[j];
            br = fmaf(c.x, vr[j*4+0], br); bi = fmaf(c.x, vi[j*4+0], bi);
            br = fmaf(c.y, vr[j*4+1], br); bi = fmaf(c.y, vi[j*4+1], bi);
            br = fmaf(c.z, vr[j*4+2], br); bi = fmaf(c.z, vi[j*4+2], bi);
            br = fmaf(c.w, vr[j*4+3], br); bi = fmaf(c.w, vi[j*4+3], bi);
        }

        uint32_t w0, w1;
        tf2x32(kC0, kC1, 0u, n, w0, w1);
        uint32_t rC = w0 ^ w1;
        tf2x32(kA0, kA1, 0u, n, w0, w1);
        uint32_t rA = w0 ^ w1;
        tf2x32(kB0, kB1, 0u, n, w0, w1);
        uint32_t rB = w0 ^ w1;

        float fu = __uint_as_float((rC >> 9) | 0x3f800000u) - 1.0f;
        float u  = __fadd_rn(__fmul_rn(fu, UDF), ULO);    // exact JAX u
        float f0 = __uint_as_float((rA >> 9) | 0x3f800000u) - 1.0f;
        float x0 = __fadd_rn(__fmul_rn(f0, NDF), NLO);
        float f1 = __uint_as_float((rB >> 9) | 0x3f800000u) - 1.0f;
        float x1 = __fadd_rn(__fmul_rn(f1, NDF), NLO);
        float nr = 1.41421356f * erfinv_fast(x0);
        float ni = 1.41421356f * erfinv_fast(x1);
        float ar = fmaf(nc, nr, br);
        float ai = fmaf(nc, ni, bi);
        float logit = __logf(fmaf(ar, ar, fmaf(ai, ai, 1e-20f)));
        float nz = 1.0f - u;
        float t = neglog_hybrid(u, nz);
        float gv = __logf(t);
        float v = logit - gv;

        uint32_t s = (q << 12) + (uint32_t)kk;
        uint32_t mu = ordmap(v);
        unsigned long long kp =
            ((unsigned long long)mu << 32) |
            (unsigned long long)(0xFFFFFFFFu - s);         // tie -> smaller s wins
        atomicMax(&keys[b * 128 + d], kp);
    }
}

// ---------------- kernel 3: gather hits + bias mean ----------------
__global__ __launch_bounds__(128) void qsl_out(const unsigned long long* __restrict__ keys,
                                               const float* __restrict__ mW,
                                               const float* __restrict__ mb,
                                               float* __restrict__ out) {
    int b = blockIdx.x, e = threadIdx.x;
    __shared__ uint32_t idx_s[128];
    unsigned long long kp = keys[b * 128 + e];
    idx_s[e] = 0xFFFFFFFFu - (uint32_t)(kp & 0xFFFFFFFFull);
    __syncthreads();

    float acc = 0.f;
#pragma unroll
    for (int n = 0; n < 16; n++) acc += mb[n * 128 + e];
    for (int dd = 0; dd < 128; dd++) {
        uint32_t m = idx_s[dd];
        if (m < 16u) acc += mW[(m * 128 + e) * 128 + dd];
    }
    out[b * 128 + e] = acc * 0.0625f;
}

// ---------------- launcher ----------------
extern "C" void kernel_launch(void* const* d_in, const int* in_sizes, int n_in,
                              void* d_out, int out_size, void* d_ws, size_t ws_size,
                              hipStream_t stream) {
    (void)in_sizes; (void)n_in; (void)out_size; (void)ws_size;
    const float* qre = (const float*)d_in[1];
    const float* qim = (const float*)d_in[2];
    const float* ang = (const float*)d_in[3];
    const float* ent = (const float*)d_in[4];
    const float* mW  = (const float*)d_in[5];
    const float* mb  = (const float*)d_in[6];
    float* out = (float*)d_out;

    char* ws = (char*)d_ws;
    float* ws_f = (float*)ws;                                      // C[256] + phase[2]
    unsigned long long* keys = (unsigned long long*)(ws + 4096);   // 512 slots
    uint32_t* Mlo = (uint32_t*)(ws + 8192);                        // 512 slots
    unsigned long long* maskArr = (unsigned long long*)(ws + 12288);            // 4 MB
    float4* whiArr = (float4*)(ws + 12288 + (size_t)NTH * 8);                   // 8 MB

    uint32_t kn[6];
    tf2x32(0u, 1u, 0u, 0u, kn[0], kn[1]);
    tf2x32(0u, 1u, 0u, 1u, kn[2], kn[3]);
    tf2x32(0u, 1u, 0u, 2u, kn[4], kn[5]);

    float coh = expf(-0.01f);
    float nc  = (0.70710678f * (1.0f - coh)) * 0.1f;

    hipLaunchKernelGGL(qsl_prep, dim3(1), dim3(512), 0, stream, ang, ent, ws_f, keys, Mlo, coh);
    hipLaunchKernelGGL(qsl_bound, dim3(2048), dim3(128, 2), 0, stream,
                       qre, qim, ws_f, Mlo, maskArr, whiArr, kn[4], kn[5]);
    hipLaunchKernelGGL(qsl_resolve, dim3(2048), dim3(128, 2), 0, stream,
                       qre, qim, ws_f, Mlo, maskArr, whiArr, keys,
                       kn[0], kn[1], kn[2], kn[3], kn[4], kn[5], nc);
    hipLaunchKernelGGL(qsl_out, dim3(4), dim3(128), 0, stream, keys, mW, mb, out);
}